// Round 7
// baseline (348.576 us; speedup 1.0000x reference)
//
#include <hip/hip_runtime.h>

// MPS encoder, segmented chain, single-barrier pipeline, BT=8.
// Grid 256x4 = 1024 blocks of 256 thr -> 4 independent blocks/CU (phase
// desync hides the product chain). Build M_n via fp8 MFMA (A-frags in two
// half-prefetched groups), M^T -> LDS MS[r][b][d]; product Q <- M^T*Q per
// batch via one 32x32x16 fp8 MFMA pair, Q register-resident (packed fp8),
// B-operand via 4 ds_bpermute lane^32 swaps.
// Scaling: core8 = fp8(16*core); Q stored = 16*true; combine /16 per seg.

#define NSITES 128
#define FEATD  64
#define BOND   32
#define OUTD   256
#define BT     8
#define SEGLEN 32
#define NSEG   (NSITES / SEGLEN)   // 4
#define NBT    (2048 / BT)         // 256

#define MS_RS  328        // row stride bytes: 8*40 + 8 pad (2-way banks on reads)
#define MS_BS  40         // batch stride bytes (32 payload + 8 pad)

typedef __attribute__((ext_vector_type(4)))  float float4v;
typedef __attribute__((ext_vector_type(16))) float float16v;

__device__ __forceinline__ unsigned pk4_fp8(float a, float b, float c, float d) {
    int v = __builtin_amdgcn_cvt_pk_fp8_f32(a, b, 0, false);
    v = __builtin_amdgcn_cvt_pk_fp8_f32(c, d, v, true);
    return (unsigned)v;
}
__device__ __forceinline__ long mklong(int lo, int hi) {
    return ((long)(unsigned)lo) | (((long)hi) << 32);
}

// cores [n][d][f][r] fp32 -> core8 [n][c=d*32+r][f] fp8 (x16), LDS transpose.
__global__ __launch_bounds__(256)
void prep_cores8(const float* __restrict__ cores, unsigned char* __restrict__ core8) {
    __shared__ float tile[FEATD][BOND + 4];
    const int nd = blockIdx.x;            // n*32 + d
    const int t  = threadIdx.x;
    const float* src = cores + (size_t)nd * (FEATD * BOND);
    {
        int base = t * 8;
        int f = base >> 5, r0 = base & 31;
        float4 v0 = *(const float4*)(src + base);
        float4 v1 = *(const float4*)(src + base + 4);
        tile[f][r0 + 0] = v0.x; tile[f][r0 + 1] = v0.y;
        tile[f][r0 + 2] = v0.z; tile[f][r0 + 3] = v0.w;
        tile[f][r0 + 4] = v1.x; tile[f][r0 + 5] = v1.y;
        tile[f][r0 + 6] = v1.z; tile[f][r0 + 7] = v1.w;
    }
    __syncthreads();
    const int r = t >> 3, f0 = (t & 7) * 8;
    const float s = 16.0f;
    unsigned lo = pk4_fp8(tile[f0 + 0][r] * s, tile[f0 + 1][r] * s,
                          tile[f0 + 2][r] * s, tile[f0 + 3][r] * s);
    unsigned hi = pk4_fp8(tile[f0 + 4][r] * s, tile[f0 + 5][r] * s,
                          tile[f0 + 6][r] * s, tile[f0 + 7][r] * s);
    uint2 w; w.x = lo; w.y = hi;
    *(uint2*)(core8 + ((size_t)nd * BOND + r) * FEATD + f0) = w;
}

__device__ __forceinline__ void product_step(const unsigned char* __restrict__ MSb,
                                             int pq[2][4], int wave, int l, int h,
                                             int paddr) {
#pragma unroll
    for (int bi = 0; bi < 2; ++bi) {
        const int bb = wave * 2 + bi;
        long a0 = *(const long*)&MSb[l * MS_RS + bb * MS_BS + 8 * h];
        long a1 = *(const long*)&MSb[l * MS_RS + bb * MS_BS + 16 + 8 * h];
        int x0 = __builtin_amdgcn_ds_bpermute(paddr, pq[bi][0]);
        int x1 = __builtin_amdgcn_ds_bpermute(paddr, pq[bi][1]);
        int x2 = __builtin_amdgcn_ds_bpermute(paddr, pq[bi][2]);
        int x3 = __builtin_amdgcn_ds_bpermute(paddr, pq[bi][3]);
        long bf0 = h ? mklong(x1, pq[bi][1]) : mklong(pq[bi][0], x0);
        long bf1 = h ? mklong(x3, pq[bi][3]) : mklong(pq[bi][2], x2);
        float16v pc;
#pragma unroll
        for (int i = 0; i < 16; ++i) pc[i] = 0.f;
        pc = __builtin_amdgcn_mfma_f32_32x32x16_fp8_fp8(a0, bf0, pc, 0, 0, 0);
        pc = __builtin_amdgcn_mfma_f32_32x32x16_fp8_fp8(a1, bf1, pc, 0, 0, 0);
        pc *= 0.0625f;   // vectorized -> v_pk_mul_f32
#pragma unroll
        for (int g = 0; g < 4; ++g)
            pq[bi][g] = (int)pk4_fp8(pc[4 * g + 0], pc[4 * g + 1],
                                     pc[4 * g + 2], pc[4 * g + 3]);
    }
}

__global__ __launch_bounds__(256, 4)   // <=128 VGPR -> 4 blocks/CU resident
void mps_seg(const float* __restrict__ x, const unsigned char* __restrict__ core8,
             unsigned char* __restrict__ Pout) {
    __shared__ __align__(16) unsigned char MS[2][BOND * MS_RS];  // 2 x 10496 B
    __shared__ __align__(16) unsigned char XS[2][BT * 72];       // 2 x   576 B

    const int t    = threadIdx.x;
    const int wave = t >> 6;          // 0..3
    const int lane = t & 63;
    const int cl   = lane & 15;
    const int q    = lane >> 4;
    const int l    = lane & 31;
    const int h    = lane >> 5;
    const int b0   = blockIdx.x * BT;
    const int seg  = blockIdx.y;
    const int n0   = seg * SEGLEN;

    // Q = P^T = 16*I, packed fp8 (fp8(16) = 0x58); wave owns batches 2w,2w+1
    int pq[2][4];
    {
        int g0 = l >> 3;
        int hm = ((l >> 2) & 1) == h;
#pragma unroll
        for (int bi = 0; bi < 2; ++bi)
#pragma unroll
            for (int g = 0; g < 4; ++g)
                pq[bi][g] = (g == g0 && hm) ? (0x58 << ((l & 3) * 8)) : 0;
    }
    const int paddr = (lane ^ 32) << 2;

    const int xb = t >> 5, xf = (t & 31) * 2;     // 8 batches x 32 pairs
    const int v0 = (wave * 256 + cl) * FEATD + q * 8;  // af lane voffset

    // preheader: XS[0] <- x(site 0); xr <- x(site 1); af0 <- site 0 (p=0 tiles)
    {
        float2 x0 = *(const float2*)(x + ((size_t)(b0 + xb) * NSITES + n0) * FEATD + xf);
        int v = __builtin_amdgcn_cvt_pk_fp8_f32(x0.x, x0.y, 0, false);
        *(unsigned short*)&XS[0][xb * 72 + xf] = (unsigned short)(v & 0xffff);
    }
    float2 xr = *(const float2*)(x + ((size_t)(b0 + xb) * NSITES + n0 + 1) * FEATD + xf);
    long af0[16], af1[16];
    {
        const unsigned char* cb = core8 + (size_t)n0 * 65536;
#pragma unroll
        for (int u = 0; u < 8; ++u) {
            const unsigned char* pu = cb + u * 2048;      // tile i = 2u
            af0[2 * u + 0] = *(const long*)(pu + v0);
            af0[2 * u + 1] = *(const long*)(pu + v0 + 32);
        }
    }
    __syncthreads();

    for (int k = 0; k < SEGLEN; ++k) {
        const int par = k & 1;
        const int n = n0 + k;
        const unsigned char* cbn = core8 + (size_t)n * 65536;

        // stage XS[par^1] <- x(k+1); issue x(k+2) load
        if (k + 1 < SEGLEN) {
            int v = __builtin_amdgcn_cvt_pk_fp8_f32(xr.x, xr.y, 0, false);
            *(unsigned short*)&XS[par ^ 1][xb * 72 + xf] = (unsigned short)(v & 0xffff);
        }
        if (k + 2 < SEGLEN)
            xr = *(const float2*)(x + ((size_t)(b0 + xb) * NSITES + n + 2) * FEATD + xf);

        // issue af1 (p=1 tiles of site k): arrives during p=0 compute
#pragma unroll
        for (int u = 0; u < 8; ++u) {
            const unsigned char* pu = cbn + u * 2048 + 1024;  // tile i = 2u+1
            af1[2 * u + 0] = *(const long*)(pu + v0);
            af1[2 * u + 1] = *(const long*)(pu + v0 + 32);
        }

        // build: m^T[c,b]; wave w covers tiles T = w*16..w*16+15, d = w*8+u
        long bx0 = *(const long*)&XS[par][(cl & 7) * 72 + q * 8];
        long bx1 = *(const long*)&XS[par][(cl & 7) * 72 + 32 + q * 8];
        {   // parity 0 (af0, prefetched last phase): rows r = 4q+g
            float4v acc[8];
#pragma unroll
            for (int u = 0; u < 8; ++u) {
                float4v z = {0.f, 0.f, 0.f, 0.f};
                z = __builtin_amdgcn_mfma_f32_16x16x32_fp8_fp8(af0[2 * u], bx0, z, 0, 0, 0);
                acc[u] = __builtin_amdgcn_mfma_f32_16x16x32_fp8_fp8(af0[2 * u + 1], bx1, z, 0, 0, 0);
            }
            if (cl < 8) {
#pragma unroll
                for (int g = 0; g < 4; ++g) {
                    unsigned d0 = pk4_fp8(acc[0][g], acc[1][g], acc[2][g], acc[3][g]);
                    unsigned d1 = pk4_fp8(acc[4][g], acc[5][g], acc[6][g], acc[7][g]);
                    *(long*)&MS[par][(4 * q + g) * MS_RS + cl * MS_BS + wave * 8] =
                        mklong((int)d0, (int)d1);
                }
            }
        }
        {   // parity 1 (af1, just issued): rows r = 16 + 4q+g
            float4v acc[8];
#pragma unroll
            for (int u = 0; u < 8; ++u) {
                float4v z = {0.f, 0.f, 0.f, 0.f};
                z = __builtin_amdgcn_mfma_f32_16x16x32_fp8_fp8(af1[2 * u], bx0, z, 0, 0, 0);
                acc[u] = __builtin_amdgcn_mfma_f32_16x16x32_fp8_fp8(af1[2 * u + 1], bx1, z, 0, 0, 0);
            }
            if (cl < 8) {
#pragma unroll
                for (int g = 0; g < 4; ++g) {
                    unsigned d0 = pk4_fp8(acc[0][g], acc[1][g], acc[2][g], acc[3][g]);
                    unsigned d1 = pk4_fp8(acc[4][g], acc[5][g], acc[6][g], acc[7][g]);
                    *(long*)&MS[par][(16 + 4 * q + g) * MS_RS + cl * MS_BS + wave * 8] =
                        mklong((int)d0, (int)d1);
                }
            }
        }

        // prefetch af0 for site k+1 (lands during product + barrier)
        if (k + 1 < SEGLEN) {
            const unsigned char* cb1 = core8 + (size_t)(n + 1) * 65536;
#pragma unroll
            for (int u = 0; u < 8; ++u) {
                const unsigned char* pu = cb1 + u * 2048;
                af0[2 * u + 0] = *(const long*)(pu + v0);
                af0[2 * u + 1] = *(const long*)(pu + v0 + 32);
            }
        }

        // product: apply M(k-1) from MS[par^1]
        if (k > 0) product_step(MS[par ^ 1], pq, wave, l, h, paddr);

        __syncthreads();
    }
    product_step(MS[(SEGLEN - 1) & 1], pq, wave, l, h, paddr);

    // dump Q (=P^T) -> Pout[seg][b][alpha=l][beta]
#pragma unroll
    for (int bi = 0; bi < 2; ++bi) {
        const int bb = wave * 2 + bi;
        unsigned char* gp = Pout + (((size_t)seg * 2048 + b0 + bb) * 1024);
#pragma unroll
        for (int g = 0; g < 4; ++g)
            *(unsigned*)(gp + l * 32 + 8 * g + 4 * h) = (unsigned)pq[bi][g];
    }
}

// combine: 8 batches/block, 256 blocks; coalesced staging, ping-pong res.
__global__ __launch_bounds__(256)
void combine(const unsigned char* __restrict__ Pout, const float* __restrict__ startv,
             const float* __restrict__ endv, const float* __restrict__ fc_w,
             const float* __restrict__ fc_b, float* __restrict__ out) {
    __shared__ __align__(16) unsigned char st[8 * 1024];
    __shared__ float resA[8][34], resB[8][34];
    __shared__ float val_lds[8];
    const int t  = threadIdx.x;
    const int b0 = blockIdx.x * 8;
    const int bt = t >> 5;        // batch 0..7
    const int c  = t & 31;        // beta

    resA[bt][c] = startv[c];

    for (int s = 0; s < NSEG; ++s) {
        {   // stage 8 KB coalesced (512 uint4, 2 per thread)
            const uint4* g = (const uint4*)(Pout + ((size_t)s * 2048 + b0) * 1024);
            *(uint4*)&st[t * 16]         = g[t];
            *(uint4*)&st[(256 + t) * 16] = g[256 + t];
        }
        __syncthreads();
        const float* rin = (s & 1) ? &resB[bt][0] : &resA[bt][0];
        float* rout      = (s & 1) ? &resA[bt][0] : &resB[bt][0];
        float acc = 0.f;
#pragma unroll
        for (int alpha = 0; alpha < BOND; ++alpha)
            acc += rin[alpha] *
                   __builtin_amdgcn_cvt_f32_fp8((int)st[bt * 1024 + alpha * 32 + c], 0);
        rout[c] = acc * 0.0625f;
        __syncthreads();
    }

    // val[bt] = res . end  (NSEG even -> resA)
    float pv = resA[bt][c] * endv[c];
#pragma unroll
    for (int off = 1; off < 32; off <<= 1) pv += __shfl_xor(pv, off, 32);
    if (c == 0) val_lds[bt] = pv;
    __syncthreads();

    const float v = val_lds[bt];
    const int j0 = c * 8;
#pragma unroll
    for (int i = 0; i < 2; ++i) {
        int j = j0 + i * 4;
        float4 w4  = *(const float4*)(fc_w + j);
        float4 bb4 = *(const float4*)(fc_b + j);
        float4 o;
        o.x = v * w4.x + bb4.x;
        o.y = v * w4.y + bb4.y;
        o.z = v * w4.z + bb4.z;
        o.w = v * w4.w + bb4.w;
        *(float4*)(out + (size_t)(b0 + bt) * OUTD + j) = o;
    }
}

extern "C" void kernel_launch(void* const* d_in, const int* in_sizes, int n_in,
                              void* d_out, int out_size, void* d_ws, size_t ws_size,
                              hipStream_t stream) {
    const float* x      = (const float*)d_in[0];
    const float* cores  = (const float*)d_in[1];
    const float* startv = (const float*)d_in[2];
    const float* endv   = (const float*)d_in[3];
    const float* fc_w   = (const float*)d_in[4];
    const float* fc_b   = (const float*)d_in[5];
    float* out = (float*)d_out;

    unsigned char* core8 = (unsigned char*)d_ws;                       // 8.4 MB
    unsigned char* Pout  = core8 + (size_t)NSITES * 1024 * FEATD;      // 8.4 MB

    prep_cores8<<<NSITES * BOND, 256, 0, stream>>>(cores, core8);
    mps_seg<<<dim3(NBT, NSEG), 256, 0, stream>>>(x, core8, Pout);
    combine<<<2048 / 8, 256, 0, stream>>>(Pout, startv, endv, fc_w, fc_b, out);
}